// Round 2
// baseline (906.106 us; speedup 1.0000x reference)
//
#include <hip/hip_runtime.h>

// MultiplicativeLayer: B=32, C=256, H*W=1024, IC=64, MC=16, OC=256
// out[b,o,p] = relu( sum_{m,i} out_w[o, m*64+i] * mask[b,m,p] * info[b,i,p] + out_b[o] )
// info = relu(info_w @ x + info_b), mask = sigmoid(mask_w @ x + mask_b)

#define C_   256
#define HW_  1024
#define IC_  64
#define MC_  16
#define OC_  256
#define PX_  64   // pixels per block

__global__ __launch_bounds__(256, 2)
void mul_layer_kernel(const float* __restrict__ x,
                      const float* __restrict__ info_w,
                      const float* __restrict__ info_b,
                      const float* __restrict__ mask_w,
                      const float* __restrict__ mask_b,
                      const float* __restrict__ out_w,
                      const float* __restrict__ out_b,
                      float* __restrict__ out)
{
    __shared__ float info_lds[IC_][PX_];   // 16 KB
    __shared__ float mask_lds[MC_][PX_];   //  4 KB

    const int lane = threadIdx.x & 63;                                  // pixel within tile
    const int wv   = __builtin_amdgcn_readfirstlane(threadIdx.x >> 6);  // wave id, SGPR-uniform
    const int bimg = blockIdx.x >> 4;   // image
    const int tile = blockIdx.x & 15;   // 64-pixel tile within image
    const int hw0  = tile * PX_;

    // ---------------- Phase 1: info (relu) + mask (sigmoid) ----------------
    // wave wv computes info rows [wv*16, wv*16+16) and mask rows [wv*4, wv*4+4)
    const float* xp = x + (size_t)bimg * C_ * HW_ + hw0 + lane;

    float racc[16];
    float macc[4];
    #pragma unroll
    for (int r = 0; r < 16; ++r) racc[r] = 0.f;
    #pragma unroll
    for (int r = 0; r < 4; ++r)  macc[r] = 0.f;

    #pragma unroll 1
    for (int c0 = 0; c0 < C_; c0 += 16) {
        float xa[16];
        #pragma unroll
        for (int j = 0; j < 16; ++j) xa[j] = xp[(size_t)(c0 + j) * HW_];  // coalesced
        #pragma unroll
        for (int r = 0; r < 16; ++r) {
            const float* wr = info_w + (wv * 16 + r) * C_ + c0;   // wave-uniform -> s_load
            #pragma unroll
            for (int j = 0; j < 16; ++j) racc[r] = fmaf(wr[j], xa[j], racc[r]);
        }
        #pragma unroll
        for (int r = 0; r < 4; ++r) {
            const float* wr = mask_w + (wv * 4 + r) * C_ + c0;    // wave-uniform -> s_load
            #pragma unroll
            for (int j = 0; j < 16; ++j) macc[r] = fmaf(wr[j], xa[j], macc[r]);
        }
    }

    #pragma unroll
    for (int r = 0; r < 16; ++r) {
        float v = racc[r] + info_b[wv * 16 + r];
        info_lds[wv * 16 + r][lane] = v > 0.f ? v : 0.f;
    }
    #pragma unroll
    for (int r = 0; r < 4; ++r) {
        float z = macc[r] + mask_b[wv * 4 + r];
        mask_lds[wv * 4 + r][lane] = 1.0f / (1.0f + expf(-z));
    }
    __syncthreads();

    // per-lane (per-pixel) info/mask into registers; conflict-free LDS reads
    float info[IC_];
    #pragma unroll
    for (int i = 0; i < IC_; ++i) info[i] = info_lds[i][lane];
    float mask[MC_];
    #pragma unroll
    for (int m = 0; m < MC_; ++m) mask[m] = mask_lds[m][lane];

    // ---------------- Phase 2: out = relu(out_w @ (mask x info) + out_b) ----------------
    // wave wv owns output channels [wv*64, wv*64+64)
    float acc[64];
    #pragma unroll
    for (int o = 0; o < 64; ++o) acc[o] = 0.f;

    const float* Wq = out_w + (size_t)(wv * 64) * (MC_ * IC_);

    #pragma unroll 1
    for (int m = 0; m < MC_; ++m) {
        const float maskm = mask[m];
        const float* Wm = Wq + m * IC_;
        #pragma unroll 1
        for (int og = 0; og < 64; og += 8) {     // 8 output channels per body
            #pragma unroll
            for (int op = 0; op < 8; op += 2) {
                const float* W0 = Wm + (size_t)(og + op    ) * (MC_ * IC_);  // wave-uniform row
                const float* W1 = Wm + (size_t)(og + op + 1) * (MC_ * IC_);  // wave-uniform row
                float t0 = 0.f, t1 = 0.f;
                #pragma unroll
                for (int i = 0; i < IC_; ++i) {
                    t0 = fmaf(W0[i], info[i], t0);   // v_fmac_f32 vD, sW, vInfo
                    t1 = fmaf(W1[i], info[i], t1);
                }
                acc[og + op]     = fmaf(maskm, t0, acc[og + op]);
                acc[og + op + 1] = fmaf(maskm, t1, acc[og + op + 1]);
            }
        }
    }

    // ---------------- epilogue: bias + relu + coalesced store ----------------
    float* op_ = out + (size_t)bimg * OC_ * HW_ + hw0 + lane;
    #pragma unroll
    for (int o = 0; o < 64; ++o) {
        const int oc = wv * 64 + o;
        float v = acc[o] + out_b[oc];
        op_[(size_t)oc * HW_] = v > 0.f ? v : 0.f;
    }
}

extern "C" void kernel_launch(void* const* d_in, const int* in_sizes, int n_in,
                              void* d_out, int out_size, void* d_ws, size_t ws_size,
                              hipStream_t stream) {
    const float* x      = (const float*)d_in[0];
    const float* info_w = (const float*)d_in[1];
    const float* info_b = (const float*)d_in[2];
    const float* mask_w = (const float*)d_in[3];
    const float* mask_b = (const float*)d_in[4];
    const float* out_w  = (const float*)d_in[5];
    const float* out_b  = (const float*)d_in[6];
    float* out = (float*)d_out;

    dim3 grid(512);   // 32 images * 16 pixel-tiles
    dim3 block(256);  // 4 waves: lane = pixel, wave = OC quarter
    hipLaunchKernelGGL(mul_layer_kernel, grid, block, 0, stream,
                       x, info_w, info_b, mask_w, mask_b, out_w, out_b, out);
}

// Round 3
// 788.052 us; speedup vs baseline: 1.1498x; 1.1498x over previous
//
#include <hip/hip_runtime.h>

// MultiplicativeLayer: B=32, C=256, H*W=1024, IC=64, MC=16, OC=256
// out[b,o,p] = relu( sum_{m,i} out_w[o, m*64+i] * mask[b,m,p] * info[b,i,p] + out_b[o] )
// info = relu(info_w @ x + info_b), mask = sigmoid(mask_w @ x + mask_b)
//
// R3: phase-2 loop-reordered so outputs complete one pair at a time.
// R2 post-mortem: acc[64] live across m-loop spilled to scratch
// (WRITE_SIZE 585 MB vs 32 MB output). No accumulator array now.

#define C_   256
#define HW_  1024
#define IC_  64
#define MC_  16
#define OC_  256
#define PX_  64   // pixels per block

__global__ __launch_bounds__(256, 2)
void mul_layer_kernel(const float* __restrict__ x,
                      const float* __restrict__ info_w,
                      const float* __restrict__ info_b,
                      const float* __restrict__ mask_w,
                      const float* __restrict__ mask_b,
                      const float* __restrict__ out_w,
                      const float* __restrict__ out_b,
                      float* __restrict__ out)
{
    __shared__ float info_lds[IC_][PX_];   // 16 KB
    __shared__ float mask_lds[MC_][PX_];   //  4 KB

    const int lane = threadIdx.x & 63;                                  // pixel within tile
    const int wv   = __builtin_amdgcn_readfirstlane(threadIdx.x >> 6);  // wave id, SGPR-uniform
    const int bimg = blockIdx.x >> 4;   // image
    const int tile = blockIdx.x & 15;   // 64-pixel tile within image
    const int hw0  = tile * PX_;

    // ---------------- Phase 1: info (relu) + mask (sigmoid) ----------------
    // wave wv computes info rows [wv*16, wv*16+16) and mask rows [wv*4, wv*4+4)
    const float* xp = x + (size_t)bimg * C_ * HW_ + hw0 + lane;

    float racc[16];
    float macc[4];
    #pragma unroll
    for (int r = 0; r < 16; ++r) racc[r] = 0.f;
    #pragma unroll
    for (int r = 0; r < 4; ++r)  macc[r] = 0.f;

    #pragma unroll 1
    for (int c0 = 0; c0 < C_; c0 += 16) {
        float xa[16];
        #pragma unroll
        for (int j = 0; j < 16; ++j) xa[j] = xp[(size_t)(c0 + j) * HW_];  // coalesced
        #pragma unroll
        for (int r = 0; r < 16; ++r) {
            const float* wr = info_w + (wv * 16 + r) * C_ + c0;   // wave-uniform -> s_load
            #pragma unroll
            for (int j = 0; j < 16; ++j) racc[r] = fmaf(wr[j], xa[j], racc[r]);
        }
        #pragma unroll
        for (int r = 0; r < 4; ++r) {
            const float* wr = mask_w + (wv * 4 + r) * C_ + c0;    // wave-uniform -> s_load
            #pragma unroll
            for (int j = 0; j < 16; ++j) macc[r] = fmaf(wr[j], xa[j], macc[r]);
        }
    }

    #pragma unroll
    for (int r = 0; r < 16; ++r) {
        float v = racc[r] + info_b[wv * 16 + r];
        info_lds[wv * 16 + r][lane] = v > 0.f ? v : 0.f;
    }
    #pragma unroll
    for (int r = 0; r < 4; ++r) {
        float z = macc[r] + mask_b[wv * 4 + r];
        mask_lds[wv * 4 + r][lane] = 1.0f / (1.0f + expf(-z));
    }
    __syncthreads();

    // per-lane (per-pixel) info/mask into registers; conflict-free LDS reads
    float info[IC_];
    #pragma unroll
    for (int i = 0; i < IC_; ++i) info[i] = info_lds[i][lane];
    float mask[MC_];
    #pragma unroll
    for (int m = 0; m < MC_; ++m) mask[m] = mask_lds[m][lane];

    // ---------------- Phase 2: out = relu(out_w @ (mask x info) + out_b) ----------------
    // wave wv owns output channels [wv*64, wv*64+64).
    // Each channel PAIR is computed to completion and stored immediately:
    // live set = info[64] + mask[16] + {t0,t1,s0,s1} -> no spill.
    float* op_ = out + (size_t)bimg * OC_ * HW_ + hw0 + lane;

    #pragma unroll 1
    for (int og = 0; og < 64; og += 2) {
        const int oc0 = wv * 64 + og;
        const float* W0 = out_w + (size_t)(oc0    ) * (MC_ * IC_);  // wave-uniform row
        const float* W1 = out_w + (size_t)(oc0 + 1) * (MC_ * IC_);  // wave-uniform row

        float t0 = 0.f, t1 = 0.f;
        #pragma unroll
        for (int m = 0; m < MC_; ++m) {
            float s0 = 0.f, s1 = 0.f;
            #pragma unroll
            for (int i = 0; i < IC_; ++i) {
                s0 = fmaf(W0[m * IC_ + i], info[i], s0);   // v_fmac_f32 vD, sW, vInfo
                s1 = fmaf(W1[m * IC_ + i], info[i], s1);
            }
            t0 = fmaf(mask[m], s0, t0);
            t1 = fmaf(mask[m], s1, t1);
        }

        float v0 = t0 + out_b[oc0];
        float v1 = t1 + out_b[oc0 + 1];
        op_[(size_t)(oc0    ) * HW_] = v0 > 0.f ? v0 : 0.f;
        op_[(size_t)(oc0 + 1) * HW_] = v1 > 0.f ? v1 : 0.f;
    }
}

extern "C" void kernel_launch(void* const* d_in, const int* in_sizes, int n_in,
                              void* d_out, int out_size, void* d_ws, size_t ws_size,
                              hipStream_t stream) {
    const float* x      = (const float*)d_in[0];
    const float* info_w = (const float*)d_in[1];
    const float* info_b = (const float*)d_in[2];
    const float* mask_w = (const float*)d_in[3];
    const float* mask_b = (const float*)d_in[4];
    const float* out_w  = (const float*)d_in[5];
    const float* out_b  = (const float*)d_in[6];
    float* out = (float*)d_out;

    dim3 grid(512);   // 32 images * 16 pixel-tiles
    dim3 block(256);  // 4 waves: lane = pixel, wave = OC quarter
    hipLaunchKernelGGL(mul_layer_kernel, grid, block, 0, stream,
                       x, info_w, info_b, mask_w, mask_b, out_w, out_b, out);
}

// Round 5
// 236.326 us; speedup vs baseline: 3.8341x; 3.3346x over previous
//
#include <hip/hip_runtime.h>

// MultiplicativeLayer: B=32, C=256, H*W=1024, IC=64, MC=16, OC=256
// out[b,o,p] = relu( sum_e out_w[o,e] * E[e,p] + out_b[o] ),  E[m*64+i, p] = mask[m,p]*info[i,p]
// R5 = R4 resubmit (infra timeout): phase-2 via mfma_f32_16x16x32_bf16 with
// 3-term hi/lo split (error ~3e-5). Requires ws_size >= 1 MB.

typedef short bf16x8 __attribute__((ext_vector_type(8)));
typedef float f32x4  __attribute__((ext_vector_type(4)));

#define C_   256
#define HW_  1024
#define IC_  64
#define MC_  16
#define OC_  256
#define PX_  64
#define K_   1024   // MC_*IC_

// ---- pre-kernel: truncation-split out_w[256][1024] fp32 -> hi/lo bf16 planes ----
// pair t covers elements 2t (low 16) and 2t+1 (high 16) of each packed uint.
__global__ __launch_bounds__(256)
void split_w(const float2* __restrict__ w2, unsigned int* __restrict__ hi,
             unsigned int* __restrict__ lo)
{
    const int t = blockIdx.x * 256 + threadIdx.x;   // 131072 pairs total
    const float2 v = w2[t];
    const unsigned int u0 = __float_as_uint(v.x);
    const unsigned int u1 = __float_as_uint(v.y);
    hi[t] = (u0 >> 16) | (u1 & 0xffff0000u);
    const float r0 = v.x - __uint_as_float(u0 & 0xffff0000u);
    const float r1 = v.y - __uint_as_float(u1 & 0xffff0000u);
    lo[t] = (__float_as_uint(r0) >> 16) | (__float_as_uint(r1) & 0xffff0000u);
}

__global__ __launch_bounds__(512, 2)
void mul_layer_kernel(const float* __restrict__ x,
                      const float* __restrict__ info_w,
                      const float* __restrict__ info_b,
                      const float* __restrict__ mask_w,
                      const float* __restrict__ mask_b,
                      const unsigned short* __restrict__ whi,
                      const unsigned short* __restrict__ wlo,
                      const float* __restrict__ out_b,
                      float* __restrict__ out)
{
    __shared__ float info_t[PX_][IC_ + 4];   // [64][68] fp32, padded (b128-aligned rows)
    __shared__ float mask_t[PX_][MC_ + 4];   // [64][20]

    const int lane = threadIdx.x & 63;                                  // pixel in phase 1
    const int wv   = __builtin_amdgcn_readfirstlane(threadIdx.x >> 6);  // 0..7
    const int bimg = blockIdx.x >> 4;
    const int tile = blockIdx.x & 15;
    const int hw0  = tile * PX_;

    // ---------------- Phase 1 (fp32): info rows wv*8..+8, mask rows wv*2..+2 ----------------
    {
        const float* xp = x + (size_t)bimg * C_ * HW_ + hw0 + lane;
        float racc[8] = {0.f,0.f,0.f,0.f,0.f,0.f,0.f,0.f};
        float macc[2] = {0.f,0.f};

        #pragma unroll 1
        for (int c0 = 0; c0 < C_; c0 += 16) {
            float xa[16];
            #pragma unroll
            for (int j = 0; j < 16; ++j) xa[j] = xp[(size_t)(c0 + j) * HW_];  // coalesced
            #pragma unroll
            for (int r = 0; r < 8; ++r) {
                const float* wr_ = info_w + (wv * 8 + r) * C_ + c0;   // wave-uniform
                #pragma unroll
                for (int j = 0; j < 16; ++j) racc[r] = fmaf(wr_[j], xa[j], racc[r]);
            }
            #pragma unroll
            for (int r = 0; r < 2; ++r) {
                const float* wr_ = mask_w + (wv * 2 + r) * C_ + c0;   // wave-uniform
                #pragma unroll
                for (int j = 0; j < 16; ++j) macc[r] = fmaf(wr_[j], xa[j], macc[r]);
            }
        }
        #pragma unroll
        for (int r = 0; r < 8; ++r) {
            float v = racc[r] + info_b[wv * 8 + r];
            info_t[lane][wv * 8 + r] = v > 0.f ? v : 0.f;   // transposed store
        }
        #pragma unroll
        for (int r = 0; r < 2; ++r) {
            float z = macc[r] + mask_b[wv * 2 + r];
            mask_t[lane][wv * 2 + r] = 1.0f / (1.0f + expf(-z));
        }
    }
    __syncthreads();
    // K-loop below is barrier-free: LDS is read-only from here.

    // ---------------- Phase 2 (MFMA): wave = 64 oc x 32 px ----------------
    const int wr = wv & 3;          // oc quarter: rows wr*64 ..
    const int wq = wv >> 2;         // px half:    cols wq*32 ..
    const int lr = lane & 15;       // A row / B col sub-index
    const int lg = lane >> 4;       // k-group (8 consecutive k each)

    f32x4 acc[4][2];
    #pragma unroll
    for (int mi = 0; mi < 4; ++mi)
        #pragma unroll
        for (int ni = 0; ni < 2; ++ni)
            acc[mi][ni] = (f32x4){0.f, 0.f, 0.f, 0.f};

    #pragma unroll 1
    for (int kc = 0; kc < 32; ++kc) {
        const int k0 = kc * 32;
        const int mb = kc >> 1;                 // mask row for this chunk

        // A fragments: lane holds W[wr*64+mi*16+lr][k0+lg*8 .. +8) for hi and lo
        bf16x8 ah[4], al[4];
        #pragma unroll
        for (int mi = 0; mi < 4; ++mi) {
            const size_t off = (size_t)(wr * 64 + mi * 16 + lr) * K_ + k0 + lg * 8;
            ah[mi] = *(const bf16x8*)(whi + off);
            al[mi] = *(const bf16x8*)(wlo + off);
        }

        #pragma unroll
        for (int ni = 0; ni < 2; ++ni) {
            const int px = wq * 32 + ni * 16 + lr;          // B col
            const int i0 = (k0 & 63) + lg * 8;              // info index base
            const f32x4 e0 = *(const f32x4*)&info_t[px][i0];
            const f32x4 e1 = *(const f32x4*)&info_t[px][i0 + 4];
            const float mk = mask_t[px][mb];

            float p[8];
            #pragma unroll
            for (int j = 0; j < 4; ++j) { p[j] = e0[j] * mk; p[j + 4] = e1[j] * mk; }

            // truncation split -> packed bf16x8 (elem j = k0+lg*8+j, low-to-high)
            union { unsigned int u[4]; bf16x8 v; } H, L;
            #pragma unroll
            for (int jp = 0; jp < 4; ++jp) {
                const unsigned int u0 = __float_as_uint(p[2 * jp]);
                const unsigned int u1 = __float_as_uint(p[2 * jp + 1]);
                H.u[jp] = (u0 >> 16) | (u1 & 0xffff0000u);
                const float r0 = p[2 * jp]     - __uint_as_float(u0 & 0xffff0000u);
                const float r1 = p[2 * jp + 1] - __uint_as_float(u1 & 0xffff0000u);
                L.u[jp] = (__float_as_uint(r0) >> 16) | (__float_as_uint(r1) & 0xffff0000u);
            }

            #pragma unroll
            for (int mi = 0; mi < 4; ++mi) {
                acc[mi][ni] = __builtin_amdgcn_mfma_f32_16x16x32_bf16(al[mi], H.v, acc[mi][ni], 0, 0, 0);
                acc[mi][ni] = __builtin_amdgcn_mfma_f32_16x16x32_bf16(ah[mi], L.v, acc[mi][ni], 0, 0, 0);
                acc[mi][ni] = __builtin_amdgcn_mfma_f32_16x16x32_bf16(ah[mi], H.v, acc[mi][ni], 0, 0, 0);
            }
        }
    }

    // ---------------- epilogue: bias + relu + store ----------------
    // D layout: row(M=oc) = lg*4 + reg, col(N=px) = lr
    float* obase = out + (size_t)bimg * OC_ * HW_ + hw0;
    #pragma unroll
    for (int mi = 0; mi < 4; ++mi) {
        #pragma unroll
        for (int r = 0; r < 4; ++r) {
            const int oc = wr * 64 + mi * 16 + lg * 4 + r;
            const float bias = out_b[oc];
            #pragma unroll
            for (int ni = 0; ni < 2; ++ni) {
                const int pxg = wq * 32 + ni * 16 + lr;
                const float v = acc[mi][ni][r] + bias;
                obase[(size_t)oc * HW_ + pxg] = v > 0.f ? v : 0.f;
            }
        }
    }
}

extern "C" void kernel_launch(void* const* d_in, const int* in_sizes, int n_in,
                              void* d_out, int out_size, void* d_ws, size_t ws_size,
                              hipStream_t stream) {
    const float* x      = (const float*)d_in[0];
    const float* info_w = (const float*)d_in[1];
    const float* info_b = (const float*)d_in[2];
    const float* mask_w = (const float*)d_in[3];
    const float* mask_b = (const float*)d_in[4];
    const float* out_w  = (const float*)d_in[5];
    const float* out_b  = (const float*)d_in[6];
    float* out = (float*)d_out;

    // d_ws layout: [0, 512KB) Whi bf16 plane, [512KB, 1MB) Wlo bf16 plane
    unsigned int* hi_u = (unsigned int*)d_ws;
    unsigned int* lo_u = hi_u + (OC_ * K_ / 2);
    const unsigned short* whi = (const unsigned short*)hi_u;
    const unsigned short* wlo = (const unsigned short*)lo_u;

    // ws is re-poisoned before every timed launch -> split must run every call.
    hipLaunchKernelGGL(split_w, dim3(512), dim3(256), 0, stream,
                       (const float2*)out_w, hi_u, lo_u);

    hipLaunchKernelGGL(mul_layer_kernel, dim3(512), dim3(512), 0, stream,
                       x, info_w, info_b, mask_w, mask_b, whi, wlo, out_b, out);
}

// Round 6
// 192.306 us; speedup vs baseline: 4.7118x; 1.2289x over previous
//
#include <hip/hip_runtime.h>

// MultiplicativeLayer: B=32, C=256, H*W=1024, IC=64, MC=16, OC=256
// out[b,o,p] = relu( sum_m mask[m,p] * sum_i W[o,m*64+i]*info[i,p] + out_b[o] )
// R6: mask folded into accumulator (B-operand = pure info, split hi/lo ONCE in
// phase 1); fragment-ordered LDS (conflict-free, imm-addressed ds_read_b128);
// fragment-ordered W planes in ws (coalesced A-loads); 1-deep A prefetch.
// R5 post-mortem: per-kc E-build VALU (3072/wave) + unprefetched A-loads left
// both pipes idle (Mfma 12%, VALU 33%, 55% stall).

typedef short bf16x8 __attribute__((ext_vector_type(8)));
typedef float f32x4  __attribute__((ext_vector_type(4)));

#define C_   256
#define HW_  1024
#define IC_  64
#define MC_  16
#define OC_  256
#define PX_  64
#define K_   1024

// ---- pre-kernel: split out_w fp32 -> hi/lo bf16, fragment-ordered ----
// dst uint4 index = ((ob*32 + t)*4 + pl*2 + mi)*64 + lane
// holds W rows ob*32+mi*16+(lane&15), k = t*32+(lane>>4)*8+(0..7), plane pl.
__global__ __launch_bounds__(256)
void split_w(const float2* __restrict__ w2, uint4* __restrict__ dst)
{
    const int tid  = blockIdx.x * 256 + threadIdx.x;   // 65536 dst uint4s
    const int lane = tid & 63;
    const int mi   = (tid >> 6) & 1;
    const int pl   = (tid >> 7) & 1;
    const int t    = (tid >> 8) & 31;
    const int ob   = (tid >> 13) & 7;

    const int row = ob * 32 + mi * 16 + (lane & 15);
    const int kq  = t * 16 + (lane >> 4) * 4;          // float2 index
    const float2* src = w2 + (size_t)row * (K_ / 2) + kq;

    unsigned int o[4];
    #pragma unroll
    for (int j = 0; j < 4; ++j) {
        const float2 v = src[j];
        const unsigned int u0 = __float_as_uint(v.x);
        const unsigned int u1 = __float_as_uint(v.y);
        if (pl == 0) {
            o[j] = (u0 >> 16) | (u1 & 0xffff0000u);
        } else {
            const float r0 = v.x - __uint_as_float(u0 & 0xffff0000u);
            const float r1 = v.y - __uint_as_float(u1 & 0xffff0000u);
            o[j] = (__float_as_uint(r0) >> 16) | (__float_as_uint(r1) & 0xffff0000u);
        }
    }
    dst[tid] = make_uint4(o[0], o[1], o[2], o[3]);
}

__global__ __launch_bounds__(512, 2)
void mul_layer_kernel(const float* __restrict__ x,
                      const float* __restrict__ info_w,
                      const float* __restrict__ info_b,
                      const float* __restrict__ mask_w,
                      const float* __restrict__ mask_b,
                      const bf16x8* __restrict__ wfrag,   // ws: fragment-ordered hi/lo
                      const float* __restrict__ out_b,
                      float* __restrict__ out)
{
    // info fragments, packed bf16, fragment-ordered:
    //   short idx(px,i) = ((px>>4)*2 + (i>>5))*512 + ((i>>3)&3)*128 + (px&15)*8 + (i&7)
    //   hi plane [0,4096), lo plane [4096,8192)
    __shared__ unsigned short ib[2 * PX_ * IC_];    // 16 KB
    __shared__ float mask_pk[MC_ * PX_];            // [m][px], 4 KB

    const int lane = threadIdx.x & 63;
    const int wv   = __builtin_amdgcn_readfirstlane(threadIdx.x >> 6);  // 0..7
    const int bimg = blockIdx.x >> 4;
    const int tile = blockIdx.x & 15;
    const int hw0  = tile * PX_;

    // ---------------- Phase 1 (fp32 GEMV): info rows wv*8..+8, mask rows wv*2..+2 ----------------
    {
        const float* xp = x + (size_t)bimg * C_ * HW_ + hw0 + lane;
        float racc[8] = {0.f,0.f,0.f,0.f,0.f,0.f,0.f,0.f};
        float macc[2] = {0.f,0.f};

        #pragma unroll 1
        for (int c0 = 0; c0 < C_; c0 += 16) {
            float xa[16];
            #pragma unroll
            for (int j = 0; j < 16; ++j) xa[j] = xp[(size_t)(c0 + j) * HW_];
            #pragma unroll
            for (int r = 0; r < 8; ++r) {
                const float* wr_ = info_w + (wv * 8 + r) * C_ + c0;   // wave-uniform
                #pragma unroll
                for (int j = 0; j < 16; ++j) racc[r] = fmaf(wr_[j], xa[j], racc[r]);
            }
            #pragma unroll
            for (int r = 0; r < 2; ++r) {
                const float* wr_ = mask_w + (wv * 2 + r) * C_ + c0;   // wave-uniform
                #pragma unroll
                for (int j = 0; j < 16; ++j) macc[r] = fmaf(wr_[j], xa[j], macc[r]);
            }
        }

        // relu + hi/lo truncation split + pack; i = wv*8+r, px = lane
        unsigned int H[4], L[4];
        #pragma unroll
        for (int rp = 0; rp < 4; ++rp) {
            float v0 = racc[2*rp]   + info_b[wv*8 + 2*rp];
            float v1 = racc[2*rp+1] + info_b[wv*8 + 2*rp+1];
            v0 = v0 > 0.f ? v0 : 0.f;
            v1 = v1 > 0.f ? v1 : 0.f;
            const unsigned int u0 = __float_as_uint(v0);
            const unsigned int u1 = __float_as_uint(v1);
            H[rp] = (u0 >> 16) | (u1 & 0xffff0000u);
            const float r0 = v0 - __uint_as_float(u0 & 0xffff0000u);
            const float r1 = v1 - __uint_as_float(u1 & 0xffff0000u);
            L[rp] = (__float_as_uint(r0) >> 16) | (__float_as_uint(r1) & 0xffff0000u);
        }
        // i = wv*8+r -> kh = wv>>2, lg = wv&3, i&7 = r  (8 consecutive shorts)
        const int sidx = ((lane >> 4) * 2 + (wv >> 2)) * 512 + (wv & 3) * 128 + (lane & 15) * 8;
        *(uint4*)(ib + sidx)                  = make_uint4(H[0], H[1], H[2], H[3]);
        *(uint4*)(ib + (PX_ * IC_) + sidx)    = make_uint4(L[0], L[1], L[2], L[3]);

        #pragma unroll
        for (int r = 0; r < 2; ++r) {
            float z = macc[r] + mask_b[wv * 2 + r];
            mask_pk[(wv * 2 + r) * PX_ + lane] = 1.0f / (1.0f + expf(-z));
        }
    }
    __syncthreads();
    // LDS read-only from here; K-loop barrier-free.

    // ---------------- Phase 2 (MFMA): wave = 32 oc x 64 px ----------------
    const int lr = lane & 15;
    const int lg = lane >> 4;

    // B reads: one addr reg + compile-time offsets. Bh(ni,kh)=Bp[(ni*2+kh)*64], Bl=+512.
    const bf16x8* Bp = (const bf16x8*)((const char*)ib + lg * 256 + lr * 16);
    const float*  Mp = mask_pk + lr;                   // Mp[m*64 + ni*16]
    // A: Ap[t*256 + pl*128 + mi*64]
    const bf16x8* Ap = wfrag + (size_t)wv * 8192 + lane;

    f32x4 acc[2][4];
    #pragma unroll
    for (int mi = 0; mi < 2; ++mi)
        #pragma unroll
        for (int ni = 0; ni < 4; ++ni)
            acc[mi][ni] = (f32x4){0.f, 0.f, 0.f, 0.f};

    // 1-deep ping-pong prefetch of A fragments (named buffers, static indexing)
    bf16x8 h0a, h0b, l0a, l0b, h1a, h1b, l1a, l1b;
    h0a = Ap[0];   h0b = Ap[64];
    l0a = Ap[128]; l0b = Ap[192];

    #pragma unroll 1
    for (int m = 0; m < MC_; ++m) {
        const int t1 = 2 * m + 1;
        // prefetch odd K-chunk
        h1a = Ap[t1 * 256];       h1b = Ap[t1 * 256 + 64];
        l1a = Ap[t1 * 256 + 128]; l1b = Ap[t1 * 256 + 192];

        f32x4 tmp[2][4];
        #pragma unroll
        for (int mi = 0; mi < 2; ++mi)
            #pragma unroll
            for (int ni = 0; ni < 4; ++ni)
                tmp[mi][ni] = (f32x4){0.f, 0.f, 0.f, 0.f};

        // kh = 0 with buffer 0
        #pragma unroll
        for (int ni = 0; ni < 4; ++ni) {
            const bf16x8 Bh = Bp[(ni * 2 + 0) * 64];
            const bf16x8 Bl = Bp[512 + (ni * 2 + 0) * 64];
            tmp[0][ni] = __builtin_amdgcn_mfma_f32_16x16x32_bf16(l0a, Bh, tmp[0][ni], 0, 0, 0);
            tmp[0][ni] = __builtin_amdgcn_mfma_f32_16x16x32_bf16(h0a, Bl, tmp[0][ni], 0, 0, 0);
            tmp[0][ni] = __builtin_amdgcn_mfma_f32_16x16x32_bf16(h0a, Bh, tmp[0][ni], 0, 0, 0);
            tmp[1][ni] = __builtin_amdgcn_mfma_f32_16x16x32_bf16(l0b, Bh, tmp[1][ni], 0, 0, 0);
            tmp[1][ni] = __builtin_amdgcn_mfma_f32_16x16x32_bf16(h0b, Bl, tmp[1][ni], 0, 0, 0);
            tmp[1][ni] = __builtin_amdgcn_mfma_f32_16x16x32_bf16(h0b, Bh, tmp[1][ni], 0, 0, 0);
        }

        // prefetch next even K-chunk into buffer 0
        if (m < MC_ - 1) {
            const int t2 = 2 * m + 2;
            h0a = Ap[t2 * 256];       h0b = Ap[t2 * 256 + 64];
            l0a = Ap[t2 * 256 + 128]; l0b = Ap[t2 * 256 + 192];
        }

        // kh = 1 with buffer 1
        #pragma unroll
        for (int ni = 0; ni < 4; ++ni) {
            const bf16x8 Bh = Bp[(ni * 2 + 1) * 64];
            const bf16x8 Bl = Bp[512 + (ni * 2 + 1) * 64];
            tmp[0][ni] = __builtin_amdgcn_mfma_f32_16x16x32_bf16(l1a, Bh, tmp[0][ni], 0, 0, 0);
            tmp[0][ni] = __builtin_amdgcn_mfma_f32_16x16x32_bf16(h1a, Bl, tmp[0][ni], 0, 0, 0);
            tmp[0][ni] = __builtin_amdgcn_mfma_f32_16x16x32_bf16(h1a, Bh, tmp[0][ni], 0, 0, 0);
            tmp[1][ni] = __builtin_amdgcn_mfma_f32_16x16x32_bf16(l1b, Bh, tmp[1][ni], 0, 0, 0);
            tmp[1][ni] = __builtin_amdgcn_mfma_f32_16x16x32_bf16(h1b, Bl, tmp[1][ni], 0, 0, 0);
            tmp[1][ni] = __builtin_amdgcn_mfma_f32_16x16x32_bf16(h1b, Bh, tmp[1][ni], 0, 0, 0);
        }

        // fold fp32 mask into accumulators (per-lane scalar: px = ni*16+lr)
        #pragma unroll
        for (int ni = 0; ni < 4; ++ni) {
            const float mk = Mp[m * 64 + ni * 16];
            #pragma unroll
            for (int mi = 0; mi < 2; ++mi)
                #pragma unroll
                for (int q = 0; q < 4; ++q)
                    acc[mi][ni][q] = fmaf(mk, tmp[mi][ni][q], acc[mi][ni][q]);
        }
    }

    // ---------------- epilogue: bias + relu + store ----------------
    // D layout: col(px) = lr (+ni*16), row(oc) = lg*4 + q (+wv*32 + mi*16)
    float* obase = out + (size_t)bimg * OC_ * HW_ + hw0;
    #pragma unroll
    for (int mi = 0; mi < 2; ++mi) {
        #pragma unroll
        for (int q = 0; q < 4; ++q) {
            const int oc = wv * 32 + mi * 16 + lg * 4 + q;
            const float bias = out_b[oc];
            #pragma unroll
            for (int ni = 0; ni < 4; ++ni) {
                const float v = acc[mi][ni][q] + bias;
                obase[(size_t)oc * HW_ + ni * 16 + lr] = v > 0.f ? v : 0.f;
            }
        }
    }
}

extern "C" void kernel_launch(void* const* d_in, const int* in_sizes, int n_in,
                              void* d_out, int out_size, void* d_ws, size_t ws_size,
                              hipStream_t stream) {
    const float* x      = (const float*)d_in[0];
    const float* info_w = (const float*)d_in[1];
    const float* info_b = (const float*)d_in[2];
    const float* mask_w = (const float*)d_in[3];
    const float* mask_b = (const float*)d_in[4];
    const float* out_w  = (const float*)d_in[5];
    const float* out_b  = (const float*)d_in[6];
    float* out = (float*)d_out;

    // ws: 1 MB fragment-ordered hi/lo bf16 W planes (re-split every call; ws re-poisoned)
    uint4* wfrag = (uint4*)d_ws;
    hipLaunchKernelGGL(split_w, dim3(256), dim3(256), 0, stream,
                       (const float2*)out_w, wfrag);

    hipLaunchKernelGGL(mul_layer_kernel, dim3(512), dim3(512), 0, stream,
                       x, info_w, info_b, mask_w, mask_b,
                       (const bf16x8*)d_ws, out_b, out);
}

// Round 7
// 187.606 us; speedup vs baseline: 4.8298x; 1.0251x over previous
//
#include <hip/hip_runtime.h>

// MultiplicativeLayer: B=32, C=256, H*W=1024, IC=64, MC=16, OC=256
// out[b,o,p] = relu( sum_m mask[m,p] * sum_i W[o,m*64+i]*info[i,p] + out_b[o] )
// R7: B fragments hoisted to registers (info is m-invariant: i = k mod 64,
// period 2 in K-chunks) -> K-loop has ZERO ds_read_b128. R6 post-mortem:
// 256 redundant B-reads/wave = ~20us/CU of LDS pipe serialized vs MFMA.

typedef short bf16x8 __attribute__((ext_vector_type(8)));
typedef float f32x4  __attribute__((ext_vector_type(4)));

#define C_   256
#define HW_  1024
#define IC_  64
#define MC_  16
#define OC_  256
#define PX_  64
#define K_   1024

// ---- pre-kernel: split out_w fp32 -> hi/lo bf16, fragment-ordered ----
// dst uint4 index = ((ob*32 + t)*4 + pl*2 + mi)*64 + lane
// holds W rows ob*32+mi*16+(lane&15), k = t*32+(lane>>4)*8+(0..7), plane pl.
__global__ __launch_bounds__(256)
void split_w(const float2* __restrict__ w2, uint4* __restrict__ dst)
{
    const int tid  = blockIdx.x * 256 + threadIdx.x;   // 65536 dst uint4s
    const int lane = tid & 63;
    const int mi   = (tid >> 6) & 1;
    const int pl   = (tid >> 7) & 1;
    const int t    = (tid >> 8) & 31;
    const int ob   = (tid >> 13) & 7;

    const int row = ob * 32 + mi * 16 + (lane & 15);
    const int kq  = t * 16 + (lane >> 4) * 4;          // float2 index
    const float2* src = w2 + (size_t)row * (K_ / 2) + kq;

    unsigned int o[4];
    #pragma unroll
    for (int j = 0; j < 4; ++j) {
        const float2 v = src[j];
        const unsigned int u0 = __float_as_uint(v.x);
        const unsigned int u1 = __float_as_uint(v.y);
        if (pl == 0) {
            o[j] = (u0 >> 16) | (u1 & 0xffff0000u);
        } else {
            const float r0 = v.x - __uint_as_float(u0 & 0xffff0000u);
            const float r1 = v.y - __uint_as_float(u1 & 0xffff0000u);
            o[j] = (__float_as_uint(r0) >> 16) | (__float_as_uint(r1) & 0xffff0000u);
        }
    }
    dst[tid] = make_uint4(o[0], o[1], o[2], o[3]);
}

__global__ __launch_bounds__(512, 2)
void mul_layer_kernel(const float* __restrict__ x,
                      const float* __restrict__ info_w,
                      const float* __restrict__ info_b,
                      const float* __restrict__ mask_w,
                      const float* __restrict__ mask_b,
                      const bf16x8* __restrict__ wfrag,   // ws: fragment-ordered hi/lo
                      const float* __restrict__ out_b,
                      float* __restrict__ out)
{
    // info fragments, packed bf16, fragment-ordered:
    //   short idx(px,i) = ((px>>4)*2 + (i>>5))*512 + ((i>>3)&3)*128 + (px&15)*8 + (i&7)
    //   hi plane [0,4096), lo plane [4096,8192) (shorts)
    __shared__ unsigned short ib[2 * PX_ * IC_];    // 16 KB
    __shared__ float mask_pk[MC_ * PX_];            // [m][px], 4 KB

    const int lane = threadIdx.x & 63;
    const int wv   = __builtin_amdgcn_readfirstlane(threadIdx.x >> 6);  // 0..7
    const int bimg = blockIdx.x >> 4;
    const int tile = blockIdx.x & 15;
    const int hw0  = tile * PX_;

    // ---------------- Phase 1 (fp32 GEMV): info rows wv*8..+8, mask rows wv*2..+2 ----------------
    {
        const float* xp = x + (size_t)bimg * C_ * HW_ + hw0 + lane;
        float racc[8] = {0.f,0.f,0.f,0.f,0.f,0.f,0.f,0.f};
        float macc[2] = {0.f,0.f};

        #pragma unroll 1
        for (int c0 = 0; c0 < C_; c0 += 16) {
            float xa[16];
            #pragma unroll
            for (int j = 0; j < 16; ++j) xa[j] = xp[(size_t)(c0 + j) * HW_];
            #pragma unroll
            for (int r = 0; r < 8; ++r) {
                const float* wr_ = info_w + (wv * 8 + r) * C_ + c0;   // wave-uniform
                #pragma unroll
                for (int j = 0; j < 16; ++j) racc[r] = fmaf(wr_[j], xa[j], racc[r]);
            }
            #pragma unroll
            for (int r = 0; r < 2; ++r) {
                const float* wr_ = mask_w + (wv * 2 + r) * C_ + c0;   // wave-uniform
                #pragma unroll
                for (int j = 0; j < 16; ++j) macc[r] = fmaf(wr_[j], xa[j], macc[r]);
            }
        }

        // relu + hi/lo truncation split + pack; i = wv*8+r, px = lane
        unsigned int H[4], L[4];
        #pragma unroll
        for (int rp = 0; rp < 4; ++rp) {
            float v0 = racc[2*rp]   + info_b[wv*8 + 2*rp];
            float v1 = racc[2*rp+1] + info_b[wv*8 + 2*rp+1];
            v0 = v0 > 0.f ? v0 : 0.f;
            v1 = v1 > 0.f ? v1 : 0.f;
            const unsigned int u0 = __float_as_uint(v0);
            const unsigned int u1 = __float_as_uint(v1);
            H[rp] = (u0 >> 16) | (u1 & 0xffff0000u);
            const float r0 = v0 - __uint_as_float(u0 & 0xffff0000u);
            const float r1 = v1 - __uint_as_float(u1 & 0xffff0000u);
            L[rp] = (__float_as_uint(r0) >> 16) | (__float_as_uint(r1) & 0xffff0000u);
        }
        // i = wv*8+r -> kh = wv>>2, lg = wv&3, i&7 = r  (8 consecutive shorts)
        const int sidx = ((lane >> 4) * 2 + (wv >> 2)) * 512 + (wv & 3) * 128 + (lane & 15) * 8;
        *(uint4*)(ib + sidx)                  = make_uint4(H[0], H[1], H[2], H[3]);
        *(uint4*)(ib + (PX_ * IC_) + sidx)    = make_uint4(L[0], L[1], L[2], L[3]);

        #pragma unroll
        for (int r = 0; r < 2; ++r) {
            float z = macc[r] + mask_b[wv * 2 + r];
            mask_pk[(wv * 2 + r) * PX_ + lane] = 1.0f / (1.0f + expf(-z));
        }
    }
    __syncthreads();
    // LDS read-only from here; K-loop barrier-free.

    // ---------------- Phase 2 (MFMA): wave = 32 oc x 64 px ----------------
    const int lr = lane & 15;
    const int lg = lane >> 4;

    // B fragments (info) fully in registers — invariant across m:
    // kh=0 covers i in [0,32), kh=1 covers i in [32,64), for every K-chunk.
    const char* ibb = (const char*)ib + lg * 256 + lr * 16;
    bf16x8 Bh[4][2], Bl[4][2];
    #pragma unroll
    for (int ni = 0; ni < 4; ++ni)
        #pragma unroll
        for (int kh = 0; kh < 2; ++kh) {
            Bh[ni][kh] = *(const bf16x8*)(ibb + (ni * 2 + kh) * 1024);
            Bl[ni][kh] = *(const bf16x8*)(ibb + 8192 + (ni * 2 + kh) * 1024);
        }

    const float*  Mp = mask_pk + lr;                   // Mp[m*64 + ni*16] (broadcast read)
    const bf16x8* Ap = wfrag + (size_t)wv * 8192 + lane;
    // A frag f = kh*4 + pl*2 + mi at Ap[m*512 + f*64]

    f32x4 acc[2][4];
    #pragma unroll
    for (int mi = 0; mi < 2; ++mi)
        #pragma unroll
        for (int ni = 0; ni < 4; ++ni)
            acc[mi][ni] = (f32x4){0.f, 0.f, 0.f, 0.f};

    bf16x8 Aa[8], Ab[8];
    #pragma unroll
    for (int f = 0; f < 8; ++f) Aa[f] = Ap[f * 64];    // m = 0

    // COMPUTE(m, A): per ni, 12 MFMA into 2 temps, fold with mask immediately.
    // A-hi frag = A[kh*4+mi], A-lo = A[kh*4+2+mi]; 3-term: lo*Bh + hi*Bl + hi*Bh.
#define COMPUTE(mm, AB)                                                              \
    {                                                                                \
        _Pragma("unroll")                                                            \
        for (int ni = 0; ni < 4; ++ni) {                                             \
            f32x4 t0 = {0.f, 0.f, 0.f, 0.f};                                         \
            f32x4 t1 = {0.f, 0.f, 0.f, 0.f};                                         \
            _Pragma("unroll")                                                        \
            for (int kh = 0; kh < 2; ++kh) {                                         \
                t0 = __builtin_amdgcn_mfma_f32_16x16x32_bf16(AB[kh*4+2], Bh[ni][kh], t0, 0, 0, 0); \
                t0 = __builtin_amdgcn_mfma_f32_16x16x32_bf16(AB[kh*4+0], Bl[ni][kh], t0, 0, 0, 0); \
                t0 = __builtin_amdgcn_mfma_f32_16x16x32_bf16(AB[kh*4+0], Bh[ni][kh], t0, 0, 0, 0); \
                t1 = __builtin_amdgcn_mfma_f32_16x16x32_bf16(AB[kh*4+3], Bh[ni][kh], t1, 0, 0, 0); \
                t1 = __builtin_amdgcn_mfma_f32_16x16x32_bf16(AB[kh*4+1], Bl[ni][kh], t1, 0, 0, 0); \
                t1 = __builtin_amdgcn_mfma_f32_16x16x32_bf16(AB[kh*4+1], Bh[ni][kh], t1, 0, 0, 0); \
            }                                                                        \
            const float mk = Mp[(mm) * 64 + ni * 16];                                \
            _Pragma("unroll")                                                        \
            for (int q = 0; q < 4; ++q) {                                            \
                acc[0][ni][q] = fmaf(mk, t0[q], acc[0][ni][q]);                      \
                acc[1][ni][q] = fmaf(mk, t1[q], acc[1][ni][q]);                      \
            }                                                                        \
        }                                                                            \
    }

    #pragma unroll 1
    for (int mp = 0; mp < 8; ++mp) {
        const int m1 = 2 * mp + 1;
        #pragma unroll
        for (int f = 0; f < 8; ++f) Ab[f] = Ap[m1 * 512 + f * 64];   // prefetch odd m
        COMPUTE(2 * mp, Aa);
        if (mp < 7) {
            #pragma unroll
            for (int f = 0; f < 8; ++f) Aa[f] = Ap[(m1 + 1) * 512 + f * 64];  // prefetch next even
        }
        COMPUTE(m1, Ab);
    }
#undef COMPUTE

    // ---------------- epilogue: bias + relu + store ----------------
    // D layout: col(px) = lr (+ni*16), row(oc) = lg*4 + q (+wv*32 + mi*16)
    float* obase = out + (size_t)bimg * OC_ * HW_ + hw0;
    #pragma unroll
    for (int mi = 0; mi < 2; ++mi) {
        #pragma unroll
        for (int q = 0; q < 4; ++q) {
            const int oc = wv * 32 + mi * 16 + lg * 4 + q;
            const float bias = out_b[oc];
            #pragma unroll
            for (int ni = 0; ni < 4; ++ni) {
                const float v = acc[mi][ni][q] + bias;
                obase[(size_t)oc * HW_ + ni * 16 + lr] = v > 0.f ? v : 0.f;
            }
        }
    }
}

extern "C" void kernel_launch(void* const* d_in, const int* in_sizes, int n_in,
                              void* d_out, int out_size, void* d_ws, size_t ws_size,
                              hipStream_t stream) {
    const float* x      = (const float*)d_in[0];
    const float* info_w = (const float*)d_in[1];
    const float* info_b = (const float*)d_in[2];
    const float* mask_w = (const float*)d_in[3];
    const float* mask_b = (const float*)d_in[4];
    const float* out_w  = (const float*)d_in[5];
    const float* out_b  = (const float*)d_in[6];
    float* out = (float*)d_out;

    // ws: 1 MB fragment-ordered hi/lo bf16 W planes (re-split every call; ws re-poisoned)
    uint4* wfrag = (uint4*)d_ws;
    hipLaunchKernelGGL(split_w, dim3(256), dim3(256), 0, stream,
                       (const float2*)out_w, wfrag);

    hipLaunchKernelGGL(mul_layer_kernel, dim3(512), dim3(512), 0, stream,
                       x, info_w, info_b, mask_w, mask_b,
                       (const bf16x8*)d_ws, out_b, out);
}

// Round 11
// 167.607 us; speedup vs baseline: 5.4061x; 1.1193x over previous
//
#include <hip/hip_runtime.h>

// MultiplicativeLayer: B=32, C=256, H*W=1024, IC=64, MC=16, OC=256
// R11 = R8/R9/R10 resubmit (3x infra timeout): phase1 (GEMV -> ws: split-bf16
// fragment-ordered info + f32 mask) and phase2 (pure-MFMA GEMM), for
// per-phase rocprof attribution. Fallback to fused R7 kernel if ws < 11 MB.

typedef short bf16x8 __attribute__((ext_vector_type(8)));
typedef float f32x4  __attribute__((ext_vector_type(4)));

#define C_   256
#define HW_  1024
#define IC_  64
#define MC_  16
#define OC_  256
#define K_   1024

#define WS_NEED (11u << 20)

__device__ inline void split2(float v0, float v1, unsigned int& h, unsigned int& l) {
    const unsigned int u0 = __float_as_uint(v0), u1 = __float_as_uint(v1);
    h = (u0 >> 16) | (u1 & 0xffff0000u);
    const float r0 = v0 - __uint_as_float(u0 & 0xffff0000u);
    const float r1 = v1 - __uint_as_float(u1 & 0xffff0000u);
    l = (__float_as_uint(r0) >> 16) | (__float_as_uint(r1) & 0xffff0000u);
}

// ---- split out_w fp32 -> hi/lo bf16, fragment-ordered (1 MB at ws+0) ----
// dst uint4 idx = ((ob*32 + t)*4 + pl*2 + mi)*64 + lane
__global__ __launch_bounds__(256)
void split_w(const float2* __restrict__ w2, uint4* __restrict__ dst)
{
    const int tid  = blockIdx.x * 256 + threadIdx.x;   // 65536
    const int lane = tid & 63;
    const int mi   = (tid >> 6) & 1;
    const int pl   = (tid >> 7) & 1;
    const int t    = (tid >> 8) & 31;
    const int ob   = (tid >> 13) & 7;

    const int row = ob * 32 + mi * 16 + (lane & 15);
    const int kq  = t * 16 + (lane >> 4) * 4;
    const float2* src = w2 + (size_t)row * (K_ / 2) + kq;

    unsigned int o[4];
    #pragma unroll
    for (int j = 0; j < 4; ++j) {
        const float2 v = src[j];
        unsigned int h, l;
        split2(v.x, v.y, h, l);
        o[j] = pl == 0 ? h : l;
    }
    dst[tid] = make_uint4(o[0], o[1], o[2], o[3]);
}

// ---- phase 1: info/mask GEMV; outputs split-bf16 fragment-ordered info + f32 mask ----
// grid 1024: bid = h*512 + tile (row-half h, 64-px tile). 4 waves; wave wv:
// info rows h*32+wv*8..+8, mask rows h*8+wv*2..+2. lane = px.
__global__ __launch_bounds__(256, 4)
void phase1_kernel(const float* __restrict__ x,
                   const float* __restrict__ info_w,
                   const float* __restrict__ info_b,
                   const float* __restrict__ mask_w,
                   const float* __restrict__ mask_b,
                   unsigned short* __restrict__ info_ws,   // 8 MB: [tile][8192 shorts]
                   float* __restrict__ mask_ws)            // 2 MB: [tile][16][64]
{
    const int lane = threadIdx.x & 63;
    const int wv   = __builtin_amdgcn_readfirstlane(threadIdx.x >> 6);  // 0..3
    const int tile = blockIdx.x & 511;
    const int h    = blockIdx.x >> 9;
    const int bimg = tile >> 4;
    const int hw0  = (tile & 15) * 64;

    const float* xp  = x + (size_t)bimg * (C_ * HW_) + hw0 + lane;
    const float* iwr = info_w + (h * 32 + wv * 8) * C_;   // wave-uniform
    const float* mwr = mask_w + (h * 8 + wv * 2) * C_;    // wave-uniform

    float racc[8] = {0.f,0.f,0.f,0.f,0.f,0.f,0.f,0.f};
    float macc[2] = {0.f,0.f};
    float xa[16], xb[16];

    #pragma unroll
    for (int j = 0; j < 16; ++j) xa[j] = xp[(size_t)j * HW_];

    // two 16-c chunks per iter, ping-pong prefetch (1 chunk ahead)
    #pragma unroll 1
    for (int c0 = 0; c0 < C_; c0 += 32) {
        #pragma unroll
        for (int j = 0; j < 16; ++j) xb[j] = xp[(size_t)(c0 + 16 + j) * HW_];
        #pragma unroll
        for (int r = 0; r < 8; ++r) {
            const float* w = iwr + r * C_ + c0;
            #pragma unroll
            for (int j = 0; j < 16; ++j) racc[r] = fmaf(w[j], xa[j], racc[r]);
        }
        #pragma unroll
        for (int r = 0; r < 2; ++r) {
            const float* w = mwr + r * C_ + c0;
            #pragma unroll
            for (int j = 0; j < 16; ++j) macc[r] = fmaf(w[j], xa[j], macc[r]);
        }
        if (c0 + 32 < C_) {
            #pragma unroll
            for (int j = 0; j < 16; ++j) xa[j] = xp[(size_t)(c0 + 32 + j) * HW_];
        }
        #pragma unroll
        for (int r = 0; r < 8; ++r) {
            const float* w = iwr + r * C_ + c0 + 16;
            #pragma unroll
            for (int j = 0; j < 16; ++j) racc[r] = fmaf(w[j], xb[j], racc[r]);
        }
        #pragma unroll
        for (int r = 0; r < 2; ++r) {
            const float* w = mwr + r * C_ + c0 + 16;
            #pragma unroll
            for (int j = 0; j < 16; ++j) macc[r] = fmaf(w[j], xb[j], macc[r]);
        }
    }

    // bias + relu + split-pack; store fragment-ordered:
    // short idx(px,i) = ((px>>4)*2 + (i>>5))*512 + ((i>>3)&3)*128 + (px&15)*8 + (i&7)
    // rows i = h*32 + wv*8 + r  ->  i>>5 = h, (i>>3)&3 = wv, i&7 = r
    unsigned int H[4], L[4];
    #pragma unroll
    for (int rp = 0; rp < 4; ++rp) {
        float v0 = racc[2*rp]   + info_b[h*32 + wv*8 + 2*rp];
        float v1 = racc[2*rp+1] + info_b[h*32 + wv*8 + 2*rp+1];
        v0 = v0 > 0.f ? v0 : 0.f;
        v1 = v1 > 0.f ? v1 : 0.f;
        split2(v0, v1, H[rp], L[rp]);
    }
    unsigned short* tb = info_ws + (size_t)tile * 8192;
    const int sidx = ((lane >> 4) * 2 + h) * 512 + wv * 128 + (lane & 15) * 8;
    *(uint4*)(tb + sidx)        = make_uint4(H[0], H[1], H[2], H[3]);
    *(uint4*)(tb + 4096 + sidx) = make_uint4(L[0], L[1], L[2], L[3]);

    #pragma unroll
    for (int r = 0; r < 2; ++r) {
        const float z = macc[r] + mask_b[h*8 + wv*2 + r];
        mask_ws[(size_t)tile * 1024 + (h*8 + wv*2 + r) * 64 + lane] =
            1.0f / (1.0f + expf(-z));
    }
}

// ---- phase 2: out = relu(sum_m mask .* (W @ info) + b), pure MFMA, no LDS ----
// grid 1024: bid = oh*512 + tile. 4 waves; wave = 32 oc x 64 px, band q = oh*4+wv.
__global__ __launch_bounds__(256, 3)
void phase2_kernel(const bf16x8* __restrict__ wfrag,
                   const unsigned short* __restrict__ info_ws,
                   const float* __restrict__ mask_ws,
                   const float* __restrict__ out_b,
                   float* __restrict__ out)
{
    const int lane = threadIdx.x & 63;
    const int wv   = __builtin_amdgcn_readfirstlane(threadIdx.x >> 6);  // 0..3
    const int tile = blockIdx.x & 511;
    const int oh   = blockIdx.x >> 9;
    const int q    = oh * 4 + wv;      // oc band: oc = q*32 ..
    const int bimg = tile >> 4;
    const int hw0  = (tile & 15) * 64;
    const int lr = lane & 15, lg = lane >> 4;

    // B fragments (info) in registers, m-invariant
    const char* ibb = (const char*)(info_ws + (size_t)tile * 8192) + lg * 256 + lr * 16;
    bf16x8 Bh[4][2], Bl[4][2];
    #pragma unroll
    for (int ni = 0; ni < 4; ++ni)
        #pragma unroll
        for (int kh = 0; kh < 2; ++kh) {
            Bh[ni][kh] = *(const bf16x8*)(ibb + (ni * 2 + kh) * 1024);
            Bl[ni][kh] = *(const bf16x8*)(ibb + 8192 + (ni * 2 + kh) * 1024);
        }

    const float*  Mp = mask_ws + (size_t)tile * 1024 + lr;   // + m*64 + ni*16
    const bf16x8* Ap = wfrag + (size_t)q * 8192 + lane;      // frag f at Ap[m*512+f*64]

    f32x4 acc[2][4];
    #pragma unroll
    for (int mi = 0; mi < 2; ++mi)
        #pragma unroll
        for (int ni = 0; ni < 4; ++ni)
            acc[mi][ni] = (f32x4){0.f, 0.f, 0.f, 0.f};

    #pragma unroll 1
    for (int m = 0; m < MC_; ++m) {
        bf16x8 A[8];
        #pragma unroll
        for (int f = 0; f < 8; ++f) A[f] = Ap[m * 512 + f * 64];
        // f = kh*4 + pl*2 + mi  (pl: 0=hi, 1=lo)
        #pragma unroll
        for (int ni = 0; ni < 4; ++ni) {
            f32x4 t0 = {0.f, 0.f, 0.f, 0.f};
            f32x4 t1 = {0.f, 0.f, 0.f, 0.f};
            #pragma unroll
            for (int kh = 0; kh < 2; ++kh) {
                t0 = __builtin_amdgcn_mfma_f32_16x16x32_bf16(A[kh*4+2], Bh[ni][kh], t0, 0, 0, 0);
                t0 = __builtin_amdgcn_mfma_f32_16x16x32_bf16(A[kh*4+0], Bl[ni][kh], t0, 0, 0, 0);
                t0 = __builtin_amdgcn_mfma_f32_16x16x32_bf16(A[kh*4+0], Bh[ni][kh], t0, 0, 0, 0);
                t1 = __builtin_amdgcn_mfma_f32_16x16x32_bf16(A[kh*4+3], Bh[ni][kh], t1, 0, 0, 0);
                t1 = __builtin_amdgcn_mfma_f32_16x16x32_bf16(A[kh*4+1], Bl[ni][kh], t1, 0, 0, 0);
                t1 = __builtin_amdgcn_mfma_f32_16x16x32_bf16(A[kh*4+1], Bh[ni][kh], t1, 0, 0, 0);
            }
            const float mk = Mp[m * 64 + ni * 16];
            #pragma unroll
            for (int qq = 0; qq < 4; ++qq) {
                acc[0][ni][qq] = fmaf(mk, t0[qq], acc[0][ni][qq]);
                acc[1][ni][qq] = fmaf(mk, t1[qq], acc[1][ni][qq]);
            }
        }
    }

    // epilogue: D row = lg*4+qq (+q*32+mi*16), col px = ni*16+lr
    float* obase = out + (size_t)bimg * OC_ * HW_ + hw0;
    #pragma unroll
    for (int mi = 0; mi < 2; ++mi) {
        #pragma unroll
        for (int qq = 0; qq < 4; ++qq) {
            const int oc = q * 32 + mi * 16 + lg * 4 + qq;
            const float bias = out_b[oc];
            #pragma unroll
            for (int ni = 0; ni < 4; ++ni) {
                const float v = acc[mi][ni][qq] + bias;
                obase[(size_t)oc * HW_ + ni * 16 + lr] = v > 0.f ? v : 0.f;
            }
        }
    }
}

// ---------------- fallback: R7 fused kernel (used only if ws too small) ----------------
__global__ __launch_bounds__(512, 2)
void fused_kernel(const float* __restrict__ x,
                  const float* __restrict__ info_w,
                  const float* __restrict__ info_b,
                  const float* __restrict__ mask_w,
                  const float* __restrict__ mask_b,
                  const bf16x8* __restrict__ wfrag,
                  const float* __restrict__ out_b,
                  float* __restrict__ out)
{
    __shared__ unsigned short ib[2 * 64 * IC_];
    __shared__ float mask_pk[MC_ * 64];

    const int lane = threadIdx.x & 63;
    const int wv   = __builtin_amdgcn_readfirstlane(threadIdx.x >> 6);
    const int bimg = blockIdx.x >> 4;
    const int tile = blockIdx.x & 15;
    const int hw0  = tile * 64;

    {
        const float* xp = x + (size_t)bimg * C_ * HW_ + hw0 + lane;
        float racc[8] = {0.f,0.f,0.f,0.f,0.f,0.f,0.f,0.f};
        float macc[2] = {0.f,0.f};
        #pragma unroll 1
        for (int c0 = 0; c0 < C_; c0 += 16) {
            float xa[16];
            #pragma unroll
            for (int j = 0; j < 16; ++j) xa[j] = xp[(size_t)(c0 + j) * HW_];
            #pragma unroll
            for (int r = 0; r < 8; ++r) {
                const float* wr_ = info_w + (wv * 8 + r) * C_ + c0;
                #pragma unroll
                for (int j = 0; j < 16; ++j) racc[r] = fmaf(wr_[j], xa[j], racc[r]);
            }
            #pragma unroll
            for (int r = 0; r < 2; ++r) {
                const float* wr_ = mask_w + (wv * 2 + r) * C_ + c0;
                #pragma unroll
                for (int j = 0; j < 16; ++j) macc[r] = fmaf(wr_[j], xa[j], macc[r]);
            }
        }
        unsigned int H[4], L[4];
        #pragma unroll
        for (int rp = 0; rp < 4; ++rp) {
            float v0 = racc[2*rp]   + info_b[wv*8 + 2*rp];
            float v1 = racc[2*rp+1] + info_b[wv*8 + 2*rp+1];
            v0 = v0 > 0.f ? v0 : 0.f;
            v1 = v1 > 0.f ? v1 : 0.f;
            split2(v0, v1, H[rp], L[rp]);
        }
        const int sidx = ((lane >> 4) * 2 + (wv >> 2)) * 512 + (wv & 3) * 128 + (lane & 15) * 8;
        *(uint4*)(ib + sidx)             = make_uint4(H[0], H[1], H[2], H[3]);
        *(uint4*)(ib + 4096 + sidx)      = make_uint4(L[0], L[1], L[2], L[3]);
        #pragma unroll
        for (int r = 0; r < 2; ++r) {
            float z = macc[r] + mask_b[wv * 2 + r];
            mask_pk[(wv * 2 + r) * 64 + lane] = 1.0f / (1.0f + expf(-z));
        }
    }
    __syncthreads();

    const int lr = lane & 15, lg = lane >> 4;
    const char* ibb = (const char*)ib + lg * 256 + lr * 16;
    bf16x8 Bh[4][2], Bl[4][2];
    #pragma unroll
    for (int ni = 0; ni < 4; ++ni)
        #pragma unroll
        for (int kh = 0; kh < 2; ++kh) {
            Bh[ni][kh] = *(const bf16x8*)(ibb + (ni * 2 + kh) * 1024);
            Bl[ni][kh] = *(const bf16x8*)(ibb + 8192 + (ni * 2 + kh) * 1024);
        }
    const float*  Mp = mask_pk + lr;
    const bf16x8* Ap = wfrag + (size_t)wv * 8192 + lane;

    f32x4 acc[2][4];
    #pragma unroll
    for (int mi = 0; mi < 2; ++mi)
        #pragma unroll
        for (int ni = 0; ni < 4; ++ni)
            acc[mi][ni] = (f32x4){0.f, 0.f, 0.f, 0.f};

    #pragma unroll 1
    for (int m = 0; m < MC_; ++m) {
        bf16x8 A[8];
        #pragma unroll
        for (int f = 0; f < 8; ++f) A[f] = Ap[m * 512 + f * 64];
        #pragma unroll
        for (int ni = 0; ni < 4; ++ni) {
            f32x4 t0 = {0.f,0.f,0.f,0.f};
            f32x4 t1 = {0.f,0.f,0.f,0.f};
            #pragma unroll
            for (int kh = 0; kh < 2; ++kh) {
                t0 = __builtin_amdgcn_mfma_f32_16x16x32_bf16(A[kh*4+2], Bh[ni][kh], t0, 0, 0, 0);
                t0 = __builtin_amdgcn_mfma_f32_16x16x32_bf16(A[kh*4+0], Bl[ni][kh], t0, 0, 0, 0);
                t0 = __builtin_amdgcn_mfma_f32_16x16x32_bf16(A[kh*4+0], Bh[ni][kh], t0, 0, 0, 0);
                t1 = __builtin_amdgcn_mfma_f32_16x16x32_bf16(A[kh*4+3], Bh[ni][kh], t1, 0, 0, 0);
                t1 = __builtin_amdgcn_mfma_f32_16x16x32_bf16(A[kh*4+1], Bl[ni][kh], t1, 0, 0, 0);
                t1 = __builtin_amdgcn_mfma_f32_16x16x32_bf16(A[kh*4+1], Bh[ni][kh], t1, 0, 0, 0);
            }
            const float mk = Mp[m * 64 + ni * 16];
            #pragma unroll
            for (int qq = 0; qq < 4; ++qq) {
                acc[0][ni][qq] = fmaf(mk, t0[qq], acc[0][ni][qq]);
                acc[1][ni][qq] = fmaf(mk, t1[qq], acc[1][ni][qq]);
            }
        }
    }

    float* obase = out + (size_t)bimg * OC_ * HW_ + hw0;
    #pragma unroll
    for (int mi = 0; mi < 2; ++mi) {
        #pragma unroll
        for (int qq = 0; qq < 4; ++qq) {
            const int oc = wv * 32 + mi * 16 + lg * 4 + qq;
            const float bias = out_b[oc];
            #pragma unroll
            for (int ni = 0; ni < 4; ++ni) {
                const float v = acc[mi][ni][qq] + bias;
                obase[(size_t)oc * HW_ + ni * 16 + lr] = v > 0.f ? v : 0.f;
            }
        }
    }
}

extern "C" void kernel_launch(void* const* d_in, const int* in_sizes, int n_in,
                              void* d_out, int out_size, void* d_ws, size_t ws_size,
                              hipStream_t stream) {
    const float* x      = (const float*)d_in[0];
    const float* info_w = (const float*)d_in[1];
    const float* info_b = (const float*)d_in[2];
    const float* mask_w = (const float*)d_in[3];
    const float* mask_b = (const float*)d_in[4];
    const float* out_w  = (const float*)d_in[5];
    const float* out_b  = (const float*)d_in[6];
    float* out = (float*)d_out;

    uint4* wfrag = (uint4*)d_ws;   // 1 MB
    hipLaunchKernelGGL(split_w, dim3(256), dim3(256), 0, stream,
                       (const float2*)out_w, wfrag);

    if (ws_size >= WS_NEED) {
        unsigned short* info_ws = (unsigned short*)((char*)d_ws + (1u << 20)); // 8 MB
        float*          mask_ws = (float*)((char*)d_ws + (9u << 20));          // 2 MB
        hipLaunchKernelGGL(phase1_kernel, dim3(1024), dim3(256), 0, stream,
                           x, info_w, info_b, mask_w, mask_b, info_ws, mask_ws);
        hipLaunchKernelGGL(phase2_kernel, dim3(1024), dim3(256), 0, stream,
                           (const bf16x8*)d_ws, info_ws, mask_ws, out_b, out);
    } else {
        hipLaunchKernelGGL(fused_kernel, dim3(512), dim3(512), 0, stream,
                           x, info_w, info_b, mask_w, mask_b,
                           (const bf16x8*)d_ws, out_b, out);
    }
}